// Round 5
// baseline (245.335 us; speedup 1.0000x reference)
//
#include <hip/hip_runtime.h>

// MinGRU stack: 3x (APL z/h + linear recurrence + maxabs-normalize) + APL out.
// B=8, T=2048, Din=D=Dout=64, P=16 knots on [-1,1].
// APL kernels: inverted loop — table slice staged in LDS (double-buffered),
// samples stream through registers. Recurrence: chunked affine scan.

#define NC 64   // chunks per sequence
#define CL 32   // timesteps per chunk (NC*CL == T == 2048)

// ---- table prep: combine (v[p], v[p+1]-v[p]) for z and h into one float4 ----
// layout: tab[(i*15 + p)*64 + o]  (slice for input-dim i is contiguous, 15 KB)
__global__ __launch_bounds__(256) void prep_dual_kernel(
    const float* __restrict__ vz, const float* __restrict__ vh,
    float4* __restrict__ tab)
{
    int idx = blockIdx.x * blockDim.x + threadIdx.x;   // over 64*15*64
    if (idx >= 64 * 15 * 64) return;
    int o = idx & 63;
    int p = (idx >> 6) % 15;
    int i = idx / (15 * 64);
    int base = (i * 16 + p) * 64 + o;
    float z0 = vz[base], z1 = vz[base + 64];
    float h0 = vh[base], h1 = vh[base + 64];
    tab[idx] = make_float4(z0, z1 - z0, h0, h1 - h0);
}

__global__ __launch_bounds__(256) void prep_out_kernel(
    const float* __restrict__ v, float2* __restrict__ tab)
{
    int idx = blockIdx.x * blockDim.x + threadIdx.x;
    if (idx >= 64 * 15 * 64) return;
    int o = idx & 63;
    int p = (idx >> 6) % 15;
    int i = idx / (15 * 64);
    int base = (i * 16 + p) * 64 + o;
    float v0 = v[base], v1 = v[base + 64];
    tab[idx] = make_float2(v0, v1 - v0);
}

// ---- APL (dual, LDS-staged): 64 samples/block, 4 waves, lane = output o ----
__global__ __launch_bounds__(256) void apl_dual_lds_kernel(
    const float* __restrict__ in, const float4* __restrict__ tab,
    float2* __restrict__ zh)
{
    __shared__ float tS[64][64];          // [i][s] clamped-scaled t, 16 KB
    __shared__ float4 tabs[2][960];       // double-buffered 15x64 slice, 30 KB

    const int tid = threadIdx.x;
    const int lane = tid & 63;
    const int w = tid >> 6;               // wave 0..3
    const size_t base = (size_t)blockIdx.x * 64;   // first sample of block

    // load x-tile (64 samples x 64 dims), compute t, store transposed [i][s]
    for (int r = tid; r < 1024; r += 256) {
        float4 xv = ((const float4*)in)[base * 16 + r];   // base*64/4 = base*16
        int s = r >> 4;
        int i0 = (r & 15) << 2;
        tS[i0 + 0][s] = fminf(fmaxf(xv.x, -1.f), 1.f) * 7.5f + 7.5f;
        tS[i0 + 1][s] = fminf(fmaxf(xv.y, -1.f), 1.f) * 7.5f + 7.5f;
        tS[i0 + 2][s] = fminf(fmaxf(xv.z, -1.f), 1.f) * 7.5f + 7.5f;
        tS[i0 + 3][s] = fminf(fmaxf(xv.w, -1.f), 1.f) * 7.5f + 7.5f;
    }
    // stage slice 0 (960 float4s across 256 threads)
    {
        tabs[0][tid]       = tab[tid];
        tabs[0][tid + 256] = tab[tid + 256];
        tabs[0][tid + 512] = tab[tid + 512];
        if (tid < 192) tabs[0][tid + 768] = tab[tid + 768];
    }
    __syncthreads();

    float accz[16], acch[16];
#pragma unroll
    for (int k = 0; k < 16; ++k) { accz[k] = 0.f; acch[k] = 0.f; }

    for (int i = 0; i < 64; ++i) {
        const int buf = i & 1;
        // prefetch next slice into regs (issue before compute: latency hides)
        float4 p0, p1, p2, p3;
        if (i < 63) {
            const float4* src = tab + (size_t)(i + 1) * 960;
            p0 = src[tid]; p1 = src[tid + 256]; p2 = src[tid + 512];
            if (tid < 192) p3 = src[tid + 768];
        }
        // interpolate this wave's 16 samples from LDS slice
        const float4* trow = (const float4*)(&tS[i][w * 16]);
#pragma unroll
        for (int q = 0; q < 4; ++q) {
            float4 tq = trow[q];                  // uniform addr -> broadcast
            float tv0 = tq.x, tv1 = tq.y, tv2 = tq.z, tv3 = tq.w;
            float tarr[4] = {tv0, tv1, tv2, tv3};
#pragma unroll
            for (int j = 0; j < 4; ++j) {
                float t = tarr[j];
                int idx = (int)t; idx = idx > 14 ? 14 : idx;
                float fr = t - (float)idx;
                float4 e = tabs[buf][idx * 64 + lane];   // contiguous 1KB/wave
                accz[q * 4 + j] += fmaf(fr, e.y, e.x);
                acch[q * 4 + j] += fmaf(fr, e.w, e.z);
            }
        }
        __syncthreads();
        if (i < 63) {
            tabs[buf ^ 1][tid]       = p0;
            tabs[buf ^ 1][tid + 256] = p1;
            tabs[buf ^ 1][tid + 512] = p2;
            if (tid < 192) tabs[buf ^ 1][tid + 768] = p3;
        }
        __syncthreads();
    }

#pragma unroll
    for (int k = 0; k < 16; ++k) {
        int s = w * 16 + k;
        float z = 1.f / (1.f + expf(-accz[k]));
        zh[(base + s) * 64 + lane] = make_float2(z, acch[k]);
    }
}

// ---- APL (single table, LDS-staged) — final output layer ----
__global__ __launch_bounds__(256) void apl_out_lds_kernel(
    const float* __restrict__ in, const float2* __restrict__ tab,
    float* __restrict__ out)
{
    __shared__ float tS[64][64];
    __shared__ float2 tabs[2][960];       // 15 KB total

    const int tid = threadIdx.x;
    const int lane = tid & 63;
    const int w = tid >> 6;
    const size_t base = (size_t)blockIdx.x * 64;

    for (int r = tid; r < 1024; r += 256) {
        float4 xv = ((const float4*)in)[base * 16 + r];
        int s = r >> 4;
        int i0 = (r & 15) << 2;
        tS[i0 + 0][s] = fminf(fmaxf(xv.x, -1.f), 1.f) * 7.5f + 7.5f;
        tS[i0 + 1][s] = fminf(fmaxf(xv.y, -1.f), 1.f) * 7.5f + 7.5f;
        tS[i0 + 2][s] = fminf(fmaxf(xv.z, -1.f), 1.f) * 7.5f + 7.5f;
        tS[i0 + 3][s] = fminf(fmaxf(xv.w, -1.f), 1.f) * 7.5f + 7.5f;
    }
    {
        tabs[0][tid]       = tab[tid];
        tabs[0][tid + 256] = tab[tid + 256];
        tabs[0][tid + 512] = tab[tid + 512];
        if (tid < 192) tabs[0][tid + 768] = tab[tid + 768];
    }
    __syncthreads();

    float acc[16];
#pragma unroll
    for (int k = 0; k < 16; ++k) acc[k] = 0.f;

    for (int i = 0; i < 64; ++i) {
        const int buf = i & 1;
        float2 p0, p1, p2, p3;
        if (i < 63) {
            const float2* src = tab + (size_t)(i + 1) * 960;
            p0 = src[tid]; p1 = src[tid + 256]; p2 = src[tid + 512];
            if (tid < 192) p3 = src[tid + 768];
        }
        const float4* trow = (const float4*)(&tS[i][w * 16]);
#pragma unroll
        for (int q = 0; q < 4; ++q) {
            float4 tq = trow[q];
            float tarr[4] = {tq.x, tq.y, tq.z, tq.w};
#pragma unroll
            for (int j = 0; j < 4; ++j) {
                float t = tarr[j];
                int idx = (int)t; idx = idx > 14 ? 14 : idx;
                float fr = t - (float)idx;
                float2 e = tabs[buf][idx * 64 + lane];
                acc[q * 4 + j] += fmaf(fr, e.y, e.x);
            }
        }
        __syncthreads();
        if (i < 63) {
            tabs[buf ^ 1][tid]       = p0;
            tabs[buf ^ 1][tid + 256] = p1;
            tabs[buf ^ 1][tid + 512] = p2;
            if (tid < 192) tabs[buf ^ 1][tid + 768] = p3;
        }
        __syncthreads();
    }

#pragma unroll
    for (int k = 0; k < 16; ++k) {
        int s = w * 16 + k;
        out[(base + s) * 64 + lane] = acc[k];
    }
}

// ---- scan pass 1: per-chunk affine summary (A, B): h_out = A*h_in + B ----
__global__ __launch_bounds__(256) void scan_pass1_kernel(
    const float2* __restrict__ zh, float2* __restrict__ chunkAB, int T)
{
    int lane = threadIdx.x & 63;
    int wid = blockIdx.x * (blockDim.x >> 6) + (threadIdx.x >> 6);  // b*NC + c
    int b = wid / NC, c = wid % NC;
    const float2* p = zh + ((size_t)b * T + (size_t)c * CL) * 64 + lane;

    float A = 1.f, Bc = 0.f;
    for (int k0 = 0; k0 < CL; k0 += 8) {
        float2 v[8];
#pragma unroll
        for (int k = 0; k < 8; ++k) v[k] = p[(size_t)(k0 + k) * 64];
#pragma unroll
        for (int k = 0; k < 8; ++k) {
            float a = 1.f - v[k].x;
            float bb = v[k].x * v[k].y;
            A *= a;
            Bc = fmaf(a, Bc, bb);
        }
    }
    chunkAB[(size_t)wid * 64 + lane] = make_float2(A, Bc);
}

// ---- scan fixup: sequential combine of NC chunk summaries per (b, d) ----
__global__ __launch_bounds__(64) void scan_fixup_kernel(
    const float2* __restrict__ chunkAB, float* __restrict__ hinit)
{
    int b = blockIdx.x;
    int d = threadIdx.x;
    const float2* p = chunkAB + (size_t)b * NC * 64 + d;
    float* o = hinit + (size_t)b * NC * 64 + d;

    float h = 0.f;  // h0 = 0
    for (int c0 = 0; c0 < NC; c0 += 8) {
        float2 ab[8];
#pragma unroll
        for (int k = 0; k < 8; ++k) ab[k] = p[(size_t)(c0 + k) * 64];
#pragma unroll
        for (int k = 0; k < 8; ++k) {
            o[(size_t)(c0 + k) * 64] = h;
            h = fmaf(ab[k].x, h, ab[k].y);
        }
    }
}

// ---- scan pass 2: replay chunk from hinit, fused maxabs-normalize ----
__global__ __launch_bounds__(256) void scan_pass2_kernel(
    const float2* __restrict__ zh, const float* __restrict__ hinit,
    float* __restrict__ out, int T)
{
    int lane = threadIdx.x & 63;
    int wid = blockIdx.x * (blockDim.x >> 6) + (threadIdx.x >> 6);  // b*NC + c
    int b = wid / NC, c = wid % NC;
    const float2* p = zh + ((size_t)b * T + (size_t)c * CL) * 64 + lane;
    float* o = out + ((size_t)b * T + (size_t)c * CL) * 64 + lane;

    float h = hinit[(size_t)wid * 64 + lane];
    for (int k0 = 0; k0 < CL; k0 += 8) {
        float2 v[8];
        float hs[8];
#pragma unroll
        for (int k = 0; k < 8; ++k) v[k] = p[(size_t)(k0 + k) * 64];
#pragma unroll
        for (int k = 0; k < 8; ++k) {
            h = fmaf(v[k].x, v[k].y - h, h);   // h += z*(hbar - h)
            hs[k] = h;
        }
#pragma unroll
        for (int k = 0; k < 8; ++k) {
            float m = fabsf(hs[k]);
            m = fmaxf(m, __shfl_xor(m, 32, 64));
            m = fmaxf(m, __shfl_xor(m, 16, 64));
            m = fmaxf(m, __shfl_xor(m, 8, 64));
            m = fmaxf(m, __shfl_xor(m, 4, 64));
            m = fmaxf(m, __shfl_xor(m, 2, 64));
            m = fmaxf(m, __shfl_xor(m, 1, 64));
            o[(size_t)(k0 + k) * 64] = hs[k] / (m + 1e-6f);
        }
    }
}

extern "C" void kernel_launch(void* const* d_in, const int* in_sizes, int n_in,
                              void* d_out, int out_size, void* d_ws, size_t ws_size,
                              hipStream_t stream) {
    const float* x    = (const float*)d_in[0];
    const float* vz0  = (const float*)d_in[1];
    const float* vh0  = (const float*)d_in[2];
    const float* vz1  = (const float*)d_in[3];
    const float* vh1  = (const float*)d_in[4];
    const float* vz2  = (const float*)d_in[5];
    const float* vh2  = (const float*)d_in[6];
    const float* vout = (const float*)d_in[7];

    const int N = in_sizes[0] / 64;   // B*T = 16384
    const int T = NC * CL;            // 2048
    const int B = N / T;              // 8
    const int NBLK = N / 64;          // 256 blocks for APL kernels

    char* ws = (char*)d_ws;
    const size_t TAB_ELEMS = (size_t)64 * 15 * 64;
    float2* zh      = (float2*)ws;                                  // 8 MB
    float*  cur     = (float*)(ws + 8388608);                       // 4 MB
    float4* tab0    = (float4*)(ws + 12582912);                     // 0.94 MB
    float4* tab1    = (float4*)(ws + 13565952);
    float4* tab2    = (float4*)(ws + 14548992);
    float2* tab_out = (float2*)(ws + 15532032);                     // 0.47 MB
    float2* chunkAB = (float2*)(ws + 16023552);                     // 256 KB
    float*  hinit   = (float*)(ws + 16285696);                      // 128 KB

    dim3 pblk(256), pgrd((TAB_ELEMS + 255) / 256);
    prep_dual_kernel<<<pgrd, pblk, 0, stream>>>(vz0, vh0, tab0);
    prep_dual_kernel<<<pgrd, pblk, 0, stream>>>(vz1, vh1, tab1);
    prep_dual_kernel<<<pgrd, pblk, 0, stream>>>(vz2, vh2, tab2);
    prep_out_kernel<<<pgrd, pblk, 0, stream>>>(vout, tab_out);

    dim3 sblk(256), sgrd(B * NC / 4);   // 4 waves (chunks) per block

    const float4* tabs[3] = {tab0, tab1, tab2};
    const float* layer_in = x;
    for (int l = 0; l < 3; ++l) {
        apl_dual_lds_kernel<<<NBLK, 256, 0, stream>>>(layer_in, tabs[l], zh);
        scan_pass1_kernel<<<sgrd, sblk, 0, stream>>>(zh, chunkAB, T);
        scan_fixup_kernel<<<B, 64, 0, stream>>>(chunkAB, hinit);
        scan_pass2_kernel<<<sgrd, sblk, 0, stream>>>(zh, hinit, cur, T);
        layer_in = cur;
    }
    apl_out_lds_kernel<<<NBLK, 256, 0, stream>>>(cur, tab_out, (float*)d_out);
}

// Round 7
// 193.961 us; speedup vs baseline: 1.2649x; 1.2649x over previous
//
#include <hip/hip_runtime.h>

// MinGRU stack: 3x (APL z/h + linear recurrence + maxabs-normalize) + APL out.
// B=8, T=2048, Din=D=Dout=64, P=16 knots on [-1,1].
// APL: direct L2 gather (one wave per sample, lane = output dim), with
// per-lane precomputed (byte-offset, frac) shuffled in the inner loop.
// Recurrence: chunked affine scan (NC chunks of CL steps).
// Prep kernels deliberately SEPARATE (not fused): the fused grid.y variant
// coincided with a post-timing divergence in round 6; rounds 4/5 with this
// structure passed post-timing re-validation.

#define WPB 4   // waves (samples) per block in APL kernels
#define NC 64   // chunks per sequence
#define CL 32   // timesteps per chunk (NC*CL == T == 2048)

// ---- table prep: combine (v[p], v[p+1]-v[p]) for z and h into one float4 ----
// layout: tab[(i*15 + p)*64 + o]  (slice for input-dim i contiguous)
__global__ __launch_bounds__(256) void prep_dual_kernel(
    const float* __restrict__ vz, const float* __restrict__ vh,
    float4* __restrict__ tab)
{
    int idx = blockIdx.x * blockDim.x + threadIdx.x;   // over 64*15*64
    if (idx >= 64 * 15 * 64) return;
    int o = idx & 63;
    int p = (idx >> 6) % 15;
    int i = idx / (15 * 64);
    int base = (i * 16 + p) * 64 + o;
    float z0 = vz[base], z1 = vz[base + 64];
    float h0 = vh[base], h1 = vh[base + 64];
    tab[idx] = make_float4(z0, z1 - z0, h0, h1 - h0);
}

__global__ __launch_bounds__(256) void prep_out_kernel(
    const float* __restrict__ v, float2* __restrict__ tab)
{
    int idx = blockIdx.x * blockDim.x + threadIdx.x;
    if (idx >= 64 * 15 * 64) return;
    int o = idx & 63;
    int p = (idx >> 6) % 15;
    int i = idx / (15 * 64);
    int base = (i * 16 + p) * 64 + o;
    float v0 = v[base], v1 = v[base + 64];
    tab[idx] = make_float2(v0, v1 - v0);
}

// ---- APL (dual): z = sigmoid(apl_z), hbar = apl_h; one wave per sample ----
// lane l precomputes (offset, frac) for ITS input dim l once; inner loop
// shuffles them: 2 shfl + 1 add + 1 dwordx4 load + 2 fma per iter.
__global__ __launch_bounds__(256) void apl_dual_kernel(
    const float* __restrict__ in, const float4* __restrict__ tab,
    float2* __restrict__ zh, int N)
{
    const int lane = threadIdx.x & 63;
    const int n = blockIdx.x * WPB + (threadIdx.x >> 6);
    if (n >= N) return;

    float xv = in[(size_t)n * 64 + lane];
    float tv = fminf(fmaxf(xv, -1.f), 1.f) * 7.5f + 7.5f;   // [0,15]
    int iv = (int)tv; iv = iv > 14 ? 14 : iv;
    float frv = tv - (float)iv;
    // byte offset of dim-l's selected row: l*15*64*16 + idx*64*16
    int offv = lane * 15360 + (iv << 10);

    const char* tb = (const char*)tab + lane * 16;   // per-lane column base
    float accz = 0.f, acch = 0.f;
#pragma unroll
    for (int i = 0; i < 64; ++i) {
        int off  = __shfl(offv, i, 64);
        float fr = __shfl(frv, i, 64);
        float4 e = *(const float4*)(tb + off);
        accz += fmaf(fr, e.y, e.x);
        acch += fmaf(fr, e.w, e.z);
    }
    float z = 1.f / (1.f + expf(-accz));
    zh[(size_t)n * 64 + lane] = make_float2(z, acch);
}

// ---- APL (single table, output layer) ----
__global__ __launch_bounds__(256) void apl_out_kernel(
    const float* __restrict__ in, const float2* __restrict__ tab,
    float* __restrict__ out, int N)
{
    const int lane = threadIdx.x & 63;
    const int n = blockIdx.x * WPB + (threadIdx.x >> 6);
    if (n >= N) return;

    float xv = in[(size_t)n * 64 + lane];
    float tv = fminf(fmaxf(xv, -1.f), 1.f) * 7.5f + 7.5f;
    int iv = (int)tv; iv = iv > 14 ? 14 : iv;
    float frv = tv - (float)iv;
    int offv = lane * 7680 + (iv << 9);   // float2 rows: 15*64*8 per dim

    const char* tb = (const char*)tab + lane * 8;
    float acc = 0.f;
#pragma unroll
    for (int i = 0; i < 64; ++i) {
        int off  = __shfl(offv, i, 64);
        float fr = __shfl(frv, i, 64);
        float2 e = *(const float2*)(tb + off);
        acc += fmaf(fr, e.y, e.x);
    }
    out[(size_t)n * 64 + lane] = acc;
}

// ---- scan pass 1: per-chunk affine summary (A, B): h_out = A*h_in + B ----
__global__ __launch_bounds__(256) void scan_pass1_kernel(
    const float2* __restrict__ zh, float2* __restrict__ chunkAB, int T)
{
    int lane = threadIdx.x & 63;
    int wid = blockIdx.x * (blockDim.x >> 6) + (threadIdx.x >> 6);  // b*NC + c
    int b = wid / NC, c = wid % NC;
    const float2* p = zh + ((size_t)b * T + (size_t)c * CL) * 64 + lane;

    float A = 1.f, Bc = 0.f;
    for (int k0 = 0; k0 < CL; k0 += 8) {
        float2 v[8];
#pragma unroll
        for (int k = 0; k < 8; ++k) v[k] = p[(size_t)(k0 + k) * 64];
#pragma unroll
        for (int k = 0; k < 8; ++k) {
            float a = 1.f - v[k].x;
            float bb = v[k].x * v[k].y;
            A *= a;
            Bc = fmaf(a, Bc, bb);
        }
    }
    chunkAB[(size_t)wid * 64 + lane] = make_float2(A, Bc);
}

// ---- scan fixup: sequential combine of NC chunk summaries per (b, d) ----
__global__ __launch_bounds__(64) void scan_fixup_kernel(
    const float2* __restrict__ chunkAB, float* __restrict__ hinit)
{
    int b = blockIdx.x;
    int d = threadIdx.x;
    const float2* p = chunkAB + (size_t)b * NC * 64 + d;
    float* o = hinit + (size_t)b * NC * 64 + d;

    float h = 0.f;  // h0 = 0
    for (int c0 = 0; c0 < NC; c0 += 8) {
        float2 ab[8];
#pragma unroll
        for (int k = 0; k < 8; ++k) ab[k] = p[(size_t)(c0 + k) * 64];
#pragma unroll
        for (int k = 0; k < 8; ++k) {
            o[(size_t)(c0 + k) * 64] = h;
            h = fmaf(ab[k].x, h, ab[k].y);
        }
    }
}

// ---- scan pass 2: replay chunk from hinit, fused maxabs-normalize ----
__global__ __launch_bounds__(256) void scan_pass2_kernel(
    const float2* __restrict__ zh, const float* __restrict__ hinit,
    float* __restrict__ out, int T)
{
    int lane = threadIdx.x & 63;
    int wid = blockIdx.x * (blockDim.x >> 6) + (threadIdx.x >> 6);  // b*NC + c
    int b = wid / NC, c = wid % NC;
    const float2* p = zh + ((size_t)b * T + (size_t)c * CL) * 64 + lane;
    float* o = out + ((size_t)b * T + (size_t)c * CL) * 64 + lane;

    float h = hinit[(size_t)wid * 64 + lane];
    for (int k0 = 0; k0 < CL; k0 += 8) {
        float2 v[8];
        float hs[8];
#pragma unroll
        for (int k = 0; k < 8; ++k) v[k] = p[(size_t)(k0 + k) * 64];
#pragma unroll
        for (int k = 0; k < 8; ++k) {
            h = fmaf(v[k].x, v[k].y - h, h);   // h += z*(hbar - h)
            hs[k] = h;
        }
#pragma unroll
        for (int k = 0; k < 8; ++k) {
            float m = fabsf(hs[k]);
            m = fmaxf(m, __shfl_xor(m, 32, 64));
            m = fmaxf(m, __shfl_xor(m, 16, 64));
            m = fmaxf(m, __shfl_xor(m, 8, 64));
            m = fmaxf(m, __shfl_xor(m, 4, 64));
            m = fmaxf(m, __shfl_xor(m, 2, 64));
            m = fmaxf(m, __shfl_xor(m, 1, 64));
            o[(size_t)(k0 + k) * 64] = hs[k] / (m + 1e-6f);
        }
    }
}

extern "C" void kernel_launch(void* const* d_in, const int* in_sizes, int n_in,
                              void* d_out, int out_size, void* d_ws, size_t ws_size,
                              hipStream_t stream) {
    const float* x    = (const float*)d_in[0];
    const float* vz0  = (const float*)d_in[1];
    const float* vh0  = (const float*)d_in[2];
    const float* vz1  = (const float*)d_in[3];
    const float* vh1  = (const float*)d_in[4];
    const float* vz2  = (const float*)d_in[5];
    const float* vh2  = (const float*)d_in[6];
    const float* vout = (const float*)d_in[7];

    const int N = in_sizes[0] / 64;   // B*T = 16384
    const int T = NC * CL;            // 2048
    const int B = N / T;              // 8

    char* ws = (char*)d_ws;
    const size_t TAB_ELEMS = (size_t)64 * 15 * 64;
    float2* zh      = (float2*)ws;                                  // 8 MB
    float*  cur     = (float*)(ws + 8388608);                       // 4 MB
    float4* tab0    = (float4*)(ws + 12582912);                     // 0.94 MB
    float4* tab1    = (float4*)(ws + 13565952);
    float4* tab2    = (float4*)(ws + 14548992);
    float2* tab_out = (float2*)(ws + 15532032);                     // 0.47 MB
    float2* chunkAB = (float2*)(ws + 16023552);                     // 256 KB
    float*  hinit   = (float*)(ws + 16285696);                      // 128 KB

    dim3 pblk(256), pgrd((TAB_ELEMS + 255) / 256);
    prep_dual_kernel<<<pgrd, pblk, 0, stream>>>(vz0, vh0, tab0);
    prep_dual_kernel<<<pgrd, pblk, 0, stream>>>(vz1, vh1, tab1);
    prep_dual_kernel<<<pgrd, pblk, 0, stream>>>(vz2, vh2, tab2);
    prep_out_kernel<<<pgrd, pblk, 0, stream>>>(vout, tab_out);

    dim3 ablk(256), agrd((N + WPB - 1) / WPB);
    dim3 sblk(256), sgrd(B * NC / 4);   // 4 waves (chunks) per block

    const float4* tabs[3] = {tab0, tab1, tab2};
    const float* layer_in = x;
    for (int l = 0; l < 3; ++l) {
        apl_dual_kernel<<<agrd, ablk, 0, stream>>>(layer_in, tabs[l], zh, N);
        scan_pass1_kernel<<<sgrd, sblk, 0, stream>>>(zh, chunkAB, T);
        scan_fixup_kernel<<<B, 64, 0, stream>>>(chunkAB, hinit);
        scan_pass2_kernel<<<sgrd, sblk, 0, stream>>>(zh, hinit, cur, T);
        layer_in = cur;
    }
    apl_out_kernel<<<agrd, ablk, 0, stream>>>(cur, tab_out, (float*)d_out, N);
}

// Round 8
// 191.985 us; speedup vs baseline: 1.2779x; 1.0103x over previous
//
#include <hip/hip_runtime.h>

// MinGRU stack: 3x (APL z/h + linear recurrence + maxabs-normalize) + APL out.
// B=8, T=2048, Din=D=Dout=64, P=16 knots on [-1,1].
// APL: direct L2 gather (one wave per sample, lane = output dim), per-lane
// precomputed (byte-offset, frac) shuffled in the inner loop, loads batched
// 4-deep for memory-level parallelism.
// Recurrence: chunked affine scan. Prep kernels kept separate (round-6 note).

#define WPB 8   // waves (samples) per block in APL kernels (512 threads)
#define NC 64   // chunks per sequence
#define CL 32   // timesteps per chunk (NC*CL == T == 2048)

// ---- table prep: combine (v[p], v[p+1]-v[p]) for z and h into one float4 ----
__global__ __launch_bounds__(256) void prep_dual_kernel(
    const float* __restrict__ vz, const float* __restrict__ vh,
    float4* __restrict__ tab)
{
    int idx = blockIdx.x * blockDim.x + threadIdx.x;   // over 64*15*64
    if (idx >= 64 * 15 * 64) return;
    int o = idx & 63;
    int p = (idx >> 6) % 15;
    int i = idx / (15 * 64);
    int base = (i * 16 + p) * 64 + o;
    float z0 = vz[base], z1 = vz[base + 64];
    float h0 = vh[base], h1 = vh[base + 64];
    tab[idx] = make_float4(z0, z1 - z0, h0, h1 - h0);
}

__global__ __launch_bounds__(256) void prep_out_kernel(
    const float* __restrict__ v, float2* __restrict__ tab)
{
    int idx = blockIdx.x * blockDim.x + threadIdx.x;
    if (idx >= 64 * 15 * 64) return;
    int o = idx & 63;
    int p = (idx >> 6) % 15;
    int i = idx / (15 * 64);
    int base = (i * 16 + p) * 64 + o;
    float v0 = v[base], v1 = v[base + 64];
    tab[idx] = make_float2(v0, v1 - v0);
}

// ---- APL (dual): z = sigmoid(apl_z), hbar = apl_h; one wave per sample ----
__global__ __launch_bounds__(512) void apl_dual_kernel(
    const float* __restrict__ in, const float4* __restrict__ tab,
    float2* __restrict__ zh, int N)
{
    const int lane = threadIdx.x & 63;
    const int n = blockIdx.x * WPB + (threadIdx.x >> 6);
    if (n >= N) return;

    float xv = in[(size_t)n * 64 + lane];
    float tv = fminf(fmaxf(xv, -1.f), 1.f) * 7.5f + 7.5f;   // [0,15]
    int iv = (int)tv; iv = iv > 14 ? 14 : iv;
    float frv = tv - (float)iv;
    int offv = lane * 15360 + (iv << 10);   // dim-l row byte offset

    const char* tb = (const char*)tab + lane * 16;
    float accz0 = 0.f, acch0 = 0.f, accz1 = 0.f, acch1 = 0.f;
#pragma unroll
    for (int i0 = 0; i0 < 64; i0 += 4) {
        // batch the 4 independent gathers: issue all before consuming any
        int of0 = __shfl(offv, i0 + 0, 64);
        int of1 = __shfl(offv, i0 + 1, 64);
        int of2 = __shfl(offv, i0 + 2, 64);
        int of3 = __shfl(offv, i0 + 3, 64);
        float fr0 = __shfl(frv, i0 + 0, 64);
        float fr1 = __shfl(frv, i0 + 1, 64);
        float fr2 = __shfl(frv, i0 + 2, 64);
        float fr3 = __shfl(frv, i0 + 3, 64);
        float4 e0 = *(const float4*)(tb + of0);
        float4 e1 = *(const float4*)(tb + of1);
        float4 e2 = *(const float4*)(tb + of2);
        float4 e3 = *(const float4*)(tb + of3);
        accz0 += fmaf(fr0, e0.y, e0.x);
        acch0 += fmaf(fr0, e0.w, e0.z);
        accz1 += fmaf(fr1, e1.y, e1.x);
        acch1 += fmaf(fr1, e1.w, e1.z);
        accz0 += fmaf(fr2, e2.y, e2.x);
        acch0 += fmaf(fr2, e2.w, e2.z);
        accz1 += fmaf(fr3, e3.y, e3.x);
        acch1 += fmaf(fr3, e3.w, e3.z);
    }
    float accz = accz0 + accz1, acch = acch0 + acch1;
    float z = 1.f / (1.f + expf(-accz));
    zh[(size_t)n * 64 + lane] = make_float2(z, acch);
}

// ---- APL (single table, output layer), 8-deep load batching ----
__global__ __launch_bounds__(512) void apl_out_kernel(
    const float* __restrict__ in, const float2* __restrict__ tab,
    float* __restrict__ out, int N)
{
    const int lane = threadIdx.x & 63;
    const int n = blockIdx.x * WPB + (threadIdx.x >> 6);
    if (n >= N) return;

    float xv = in[(size_t)n * 64 + lane];
    float tv = fminf(fmaxf(xv, -1.f), 1.f) * 7.5f + 7.5f;
    int iv = (int)tv; iv = iv > 14 ? 14 : iv;
    float frv = tv - (float)iv;
    int offv = lane * 7680 + (iv << 9);

    const char* tb = (const char*)tab + lane * 8;
    float acc0 = 0.f, acc1 = 0.f;
#pragma unroll
    for (int i0 = 0; i0 < 64; i0 += 8) {
        int of[8]; float fr[8]; float2 e[8];
#pragma unroll
        for (int j = 0; j < 8; ++j) of[j] = __shfl(offv, i0 + j, 64);
#pragma unroll
        for (int j = 0; j < 8; ++j) fr[j] = __shfl(frv, i0 + j, 64);
#pragma unroll
        for (int j = 0; j < 8; ++j) e[j] = *(const float2*)(tb + of[j]);
#pragma unroll
        for (int j = 0; j < 8; j += 2) {
            acc0 += fmaf(fr[j], e[j].y, e[j].x);
            acc1 += fmaf(fr[j + 1], e[j + 1].y, e[j + 1].x);
        }
    }
    out[(size_t)n * 64 + lane] = acc0 + acc1;
}

// ---- scan pass 1: per-chunk affine summary (A, B): h_out = A*h_in + B ----
__global__ __launch_bounds__(256) void scan_pass1_kernel(
    const float2* __restrict__ zh, float2* __restrict__ chunkAB, int T)
{
    int lane = threadIdx.x & 63;
    int wid = blockIdx.x * (blockDim.x >> 6) + (threadIdx.x >> 6);  // b*NC + c
    int b = wid / NC, c = wid % NC;
    const float2* p = zh + ((size_t)b * T + (size_t)c * CL) * 64 + lane;

    float A = 1.f, Bc = 0.f;
    for (int k0 = 0; k0 < CL; k0 += 8) {
        float2 v[8];
#pragma unroll
        for (int k = 0; k < 8; ++k) v[k] = p[(size_t)(k0 + k) * 64];
#pragma unroll
        for (int k = 0; k < 8; ++k) {
            float a = 1.f - v[k].x;
            float bb = v[k].x * v[k].y;
            A *= a;
            Bc = fmaf(a, Bc, bb);
        }
    }
    chunkAB[(size_t)wid * 64 + lane] = make_float2(A, Bc);
}

// ---- scan fixup: sequential combine of NC chunk summaries per (b, d) ----
__global__ __launch_bounds__(64) void scan_fixup_kernel(
    const float2* __restrict__ chunkAB, float* __restrict__ hinit)
{
    int b = blockIdx.x;
    int d = threadIdx.x;
    const float2* p = chunkAB + (size_t)b * NC * 64 + d;
    float* o = hinit + (size_t)b * NC * 64 + d;

    float h = 0.f;  // h0 = 0
    for (int c0 = 0; c0 < NC; c0 += 8) {
        float2 ab[8];
#pragma unroll
        for (int k = 0; k < 8; ++k) ab[k] = p[(size_t)(c0 + k) * 64];
#pragma unroll
        for (int k = 0; k < 8; ++k) {
            o[(size_t)(c0 + k) * 64] = h;
            h = fmaf(ab[k].x, h, ab[k].y);
        }
    }
}

// ---- scan pass 2: replay chunk from hinit, fused maxabs-normalize ----
__global__ __launch_bounds__(256) void scan_pass2_kernel(
    const float2* __restrict__ zh, const float* __restrict__ hinit,
    float* __restrict__ out, int T)
{
    int lane = threadIdx.x & 63;
    int wid = blockIdx.x * (blockDim.x >> 6) + (threadIdx.x >> 6);  // b*NC + c
    int b = wid / NC, c = wid % NC;
    const float2* p = zh + ((size_t)b * T + (size_t)c * CL) * 64 + lane;
    float* o = out + ((size_t)b * T + (size_t)c * CL) * 64 + lane;

    float h = hinit[(size_t)wid * 64 + lane];
    for (int k0 = 0; k0 < CL; k0 += 8) {
        float2 v[8];
        float hs[8];
#pragma unroll
        for (int k = 0; k < 8; ++k) v[k] = p[(size_t)(k0 + k) * 64];
#pragma unroll
        for (int k = 0; k < 8; ++k) {
            h = fmaf(v[k].x, v[k].y - h, h);   // h += z*(hbar - h)
            hs[k] = h;
        }
#pragma unroll
        for (int k = 0; k < 8; ++k) {
            float m = fabsf(hs[k]);
            m = fmaxf(m, __shfl_xor(m, 32, 64));
            m = fmaxf(m, __shfl_xor(m, 16, 64));
            m = fmaxf(m, __shfl_xor(m, 8, 64));
            m = fmaxf(m, __shfl_xor(m, 4, 64));
            m = fmaxf(m, __shfl_xor(m, 2, 64));
            m = fmaxf(m, __shfl_xor(m, 1, 64));
            o[(size_t)(k0 + k) * 64] = hs[k] / (m + 1e-6f);
        }
    }
}

extern "C" void kernel_launch(void* const* d_in, const int* in_sizes, int n_in,
                              void* d_out, int out_size, void* d_ws, size_t ws_size,
                              hipStream_t stream) {
    const float* x    = (const float*)d_in[0];
    const float* vz0  = (const float*)d_in[1];
    const float* vh0  = (const float*)d_in[2];
    const float* vz1  = (const float*)d_in[3];
    const float* vh1  = (const float*)d_in[4];
    const float* vz2  = (const float*)d_in[5];
    const float* vh2  = (const float*)d_in[6];
    const float* vout = (const float*)d_in[7];

    const int N = in_sizes[0] / 64;   // B*T = 16384
    const int T = NC * CL;            // 2048
    const int B = N / T;              // 8

    char* ws = (char*)d_ws;
    const size_t TAB_ELEMS = (size_t)64 * 15 * 64;
    float2* zh      = (float2*)ws;                                  // 8 MB
    float*  cur     = (float*)(ws + 8388608);                       // 4 MB
    float4* tab0    = (float4*)(ws + 12582912);                     // 0.94 MB
    float4* tab1    = (float4*)(ws + 13565952);
    float4* tab2    = (float4*)(ws + 14548992);
    float2* tab_out = (float2*)(ws + 15532032);                     // 0.47 MB
    float2* chunkAB = (float2*)(ws + 16023552);                     // 256 KB
    float*  hinit   = (float*)(ws + 16285696);                      // 128 KB

    dim3 pblk(256), pgrd((TAB_ELEMS + 255) / 256);
    prep_dual_kernel<<<pgrd, pblk, 0, stream>>>(vz0, vh0, tab0);
    prep_dual_kernel<<<pgrd, pblk, 0, stream>>>(vz1, vh1, tab1);
    prep_dual_kernel<<<pgrd, pblk, 0, stream>>>(vz2, vh2, tab2);
    prep_out_kernel<<<pgrd, pblk, 0, stream>>>(vout, tab_out);

    dim3 ablk(64 * WPB), agrd((N + WPB - 1) / WPB);
    dim3 sblk(256), sgrd(B * NC / 4);   // 4 waves (chunks) per block

    const float4* tabs[3] = {tab0, tab1, tab2};
    const float* layer_in = x;
    for (int l = 0; l < 3; ++l) {
        apl_dual_kernel<<<agrd, ablk, 0, stream>>>(layer_in, tabs[l], zh, N);
        scan_pass1_kernel<<<sgrd, sblk, 0, stream>>>(zh, chunkAB, T);
        scan_fixup_kernel<<<B, 64, 0, stream>>>(chunkAB, hinit);
        scan_pass2_kernel<<<sgrd, sblk, 0, stream>>>(zh, hinit, cur, T);
        layer_in = cur;
    }
    apl_out_kernel<<<agrd, ablk, 0, stream>>>(cur, tab_out, (float*)d_out, N);
}